// Round 5
// baseline (50.270 us; speedup 1.0000x reference)
//
#include <hip/hip_runtime.h>

#define N_ 256
#define C_ 3
#define T_ 600
#define V_ 25
#define GPP 15                    // row-pairs per unit
#define UPS (300 / GPP)           // 20 units per (n,c) slab
#define UPB 10                    // units per 256-thread block (250 active)
#define NBLK (N_ * C_ * UPS / UPB) // 1536 blocks

// Unit = 25 threads; thread p owns float4 slot p of each 100-float row-pair
// (elements 4p..4p+3). Static element->joint map (bijective over the pair):
//   p<=11: row0 of joints (2p, 2p+1); p==12: row0 of j24 (.xy) + row1 of j0 (.zw);
//   p>=13: row1 of joints (2p-25, 2p-24).
// sq(x-y): pure f4 streams of x AND y tile the pair exactly -> 2 static bins/lane.
// motion: joint j owned by thread p=j/2 (j=24 -> p=12). Owner loads the
// complementary row of ITS joints as float2 (same lines as neighbors' f4 loads
// -> L1 hits, no extra fabric traffic). Cross-pair diff via carried register;
// unit seam sealed by one extra x-f4 of the next pair. Exact 599-diff partition.
__global__ __launch_bounds__(256) void slab_kernel(const float* __restrict__ x,
                                                   const float* __restrict__ y,
                                                   float* __restrict__ absws,
                                                   float* __restrict__ sqws) {
    __shared__ float binAbs[32], binSq[32];
    const int t = threadIdx.x;
    if (t < 32) { binAbs[t] = 0.f; binSq[t] = 0.f; }
    __syncthreads();

    const int  unitg  = blockIdx.x * UPB + t / V_;
    const int  p      = t % V_;
    const bool active = (t < UPB * V_);
    const int  slab   = unitg / UPS;          // n*3 + c (valid when active)
    const int  n      = slab / C_;
    const int  g0     = (unitg % UPS) * GPP;

    float sqA = 0.f, sqB = 0.f, mA = 0.f, mB = 0.f;

    if (active) {
        const float* __restrict__ xs = x + (size_t)slab * 30000;
        const float* __restrict__ ys = y + (size_t)slab * 30000;
        const int e4 = 4 * p;

        float c0 = 0.f, c1 = 0.f, c2 = 0.f, c3 = 0.f;   // carried row1 of prev pair
        bool first = true;

        for (int b = 0; b < GPP; b += 5) {
            float4 xf[5], yf[5];
            float2 fa[5], fb[5];
            #pragma unroll
            for (int k = 0; k < 5; ++k) {
                const int g = g0 + b + k;
                const float* pb = xs + g * 100;
                xf[k] = *reinterpret_cast<const float4*>(pb + e4);
                yf[k] = *reinterpret_cast<const float4*>(ys + g * 100 + e4);
                if (p <= 11) {
                    fa[k] = *reinterpret_cast<const float2*>(pb + 50 + e4);
                    fb[k] = *reinterpret_cast<const float2*>(pb + 52 + e4);
                } else if (p == 12) {
                    fa[k] = *reinterpret_cast<const float2*>(pb + 98);
                }
            }
            #pragma unroll
            for (int k = 0; k < 5; ++k) {
                const float4 a = xf[k], q = yf[k];
                const float e0 = a.x - q.x, e1 = a.y - q.y;
                const float e2 = a.z - q.z, e3 = a.w - q.w;
                sqA += e0 * e0 + e1 * e1;
                sqB += e2 * e2 + e3 * e3;
                if (p <= 11) {
                    mA += fabsf(fa[k].x - a.x) + fabsf(fa[k].y - a.y);
                    mB += fabsf(fb[k].x - a.z) + fabsf(fb[k].y - a.w);
                    if (!first) {
                        mA += fabsf(a.x - c0) + fabsf(a.y - c1);
                        mB += fabsf(a.z - c2) + fabsf(a.w - c3);
                    }
                    c0 = fa[k].x; c1 = fa[k].y; c2 = fb[k].x; c3 = fb[k].y;
                } else if (p == 12) {
                    mA += fabsf(fa[k].x - a.x) + fabsf(fa[k].y - a.y);
                    if (!first) {
                        mA += fabsf(a.x - c0) + fabsf(a.y - c1);
                    }
                    c0 = fa[k].x; c1 = fa[k].y;
                }
                first = false;
            }
        }

        // seam: row1 of last pair -> row0 of next unit's first pair
        if (g0 + GPP < 300 && p <= 12) {
            const float4 s = *reinterpret_cast<const float4*>(xs + (size_t)(g0 + GPP) * 100 + e4);
            mA += fabsf(s.x - c0) + fabsf(s.y - c1);
            if (p <= 11) mB += fabsf(s.z - c2) + fabsf(s.w - c3);
        }

        const int jA = (p <= 11) ? 2 * p     : (p == 12 ? 24 : 2 * p - 25);
        const int jB = (p <= 11) ? 2 * p + 1 : (p == 12 ? 0  : 2 * p - 24);
        atomicAdd(&binSq[jA], sqA);
        atomicAdd(&binSq[jB], sqB);
        if (p <= 12) {
            atomicAdd(&binAbs[jA], mA);
            if (p <= 11) atomicAdd(&binAbs[jB], mB);
        }
    }
    __syncthreads();

    if (t < V_) {
        atomicAdd(&absws[n * V_ + t], binAbs[t]);   // note: all units in a block share n
        atomicAdd(&sqws[n * V_ + t], binSq[t]);
    }
}

// final = (1/TOT) * sum_n sum_v (V * abs[n,v] / sum_v abs[n,.]) * sq[n,v]
__global__ __launch_bounds__(256) void finalize_kernel(const float* __restrict__ absws,
                                                       const float* __restrict__ sqws,
                                                       float* __restrict__ out) {
    const int n = threadIdx.x;
    float sumAbs = 0.0f;
    #pragma unroll
    for (int v = 0; v < V_; ++v) sumAbs += absws[n * V_ + v];
    float sumW = 0.0f;
    #pragma unroll
    for (int v = 0; v < V_; ++v) sumW += absws[n * V_ + v] * sqws[n * V_ + v];
    float partial = (float)V_ * sumW / sumAbs;

    __shared__ float red[256];
    red[n] = partial;
    __syncthreads();
    for (int s = 128; s > 0; s >>= 1) {
        if (n < s) red[n] += red[n + s];
        __syncthreads();
    }
    if (n == 0) out[0] = red[0] / (float)((size_t)N_ * C_ * T_ * V_ * 2);
}

extern "C" void kernel_launch(void* const* d_in, const int* in_sizes, int n_in,
                              void* d_out, int out_size, void* d_ws, size_t ws_size,
                              hipStream_t stream) {
    const float* x = (const float*)d_in[0];
    const float* y = (const float*)d_in[1];
    float* out   = (float*)d_out;
    float* absws = (float*)d_ws;              // N*V floats
    float* sqws  = absws + N_ * V_;           // N*V floats

    hipMemsetAsync(d_ws, 0, (size_t)(2 * N_ * V_) * sizeof(float), stream);

    slab_kernel<<<NBLK, 256, 0, stream>>>(x, y, absws, sqws);

    finalize_kernel<<<1, 256, 0, stream>>>(absws, sqws, out);
}

// Round 6
// 40.189 us; speedup vs baseline: 1.2509x; 1.2509x over previous
//
#include <hip/hip_runtime.h>

#define N_ 256
#define C_ 3
#define T_ 600
#define V_ 25
#define M_ 2
#define NSLAB (N_ * C_)        // 768
#define TY 20
#define CH (T_ / TY)           // 30 t-rows per ty-chunk

// One block per (n,c) slab. blockDim = (25,20): tx = joint v (ALL lanes active;
// linear wave packing gives 500/512 = 97.6% lane-slot utilization vs 78% for
// (32,16)). ty owns a contiguous 30-row t-chunk. float2 = (m0,m1) of joint v.
// Rolling register carries x[t-1] for the temporal diff; chunk seam sealed by
// one boundary x-load (diff t1-1 -> t1). Exact 599-diff partition:
// 19 chunks x (29+1 seam) + 29 = 599. Partials written DISJOINTLY (no memset,
// no global atomics): absP[slab*25+v], sqP[slab*25+v].
__global__ __launch_bounds__(512) void slab_kernel(const float* __restrict__ x,
                                                   const float* __restrict__ y,
                                                   float* __restrict__ absP,
                                                   float* __restrict__ sqP) {
    const int slab = blockIdx.x;          // n*3 + c
    const int tx   = threadIdx.x;         // 0..24 == joint v
    const int ty   = threadIdx.y;         // 0..19

    const float2* __restrict__ xs = reinterpret_cast<const float2*>(x) + (size_t)slab * (T_ * V_);
    const float2* __restrict__ ys = reinterpret_cast<const float2*>(y) + (size_t)slab * (T_ * V_);

    const int t0 = ty * CH;
    const int t1 = t0 + CH;

    float2 xc = xs[t0 * V_ + tx];
    float2 yc = ys[t0 * V_ + tx];
    float ex = xc.x - yc.x, ey = xc.y - yc.y;
    float sq = ex * ex + ey * ey;
    float mv = 0.0f;

    for (int t = t0 + 1; t < t1; ++t) {
        float2 xn = xs[t * V_ + tx];
        float2 yn = ys[t * V_ + tx];
        mv += fabsf(xn.x - xc.x) + fabsf(xn.y - xc.y);
        ex = xn.x - yn.x; ey = xn.y - yn.y;
        sq += ex * ex + ey * ey;
        xc = xn;
    }
    if (t1 < T_) {                         // seam diff (t1-1 -> t1)
        float2 xn = xs[t1 * V_ + tx];
        mv += fabsf(xn.x - xc.x) + fabsf(xn.y - xc.y);
    }

    __shared__ float redA[TY][V_ + 1];
    __shared__ float redS[TY][V_ + 1];
    redA[ty][tx] = mv;
    redS[ty][tx] = sq;
    __syncthreads();

    if (ty == 0) {
        float a = 0.0f, s = 0.0f;
        #pragma unroll
        for (int j = 0; j < TY; ++j) { a += redA[j][tx]; s += redS[j][tx]; }
        absP[slab * V_ + tx] = a;          // disjoint plain stores
        sqP[slab * V_ + tx]  = s;
    }
}

// final = (1/TOT) * sum_n sum_v (V * abs[n,v] / sum_v abs[n,.]) * sq[n,v]
// Reads the 3 per-c partials per (n,v) and reduces. One block, 256 threads = 256 n.
__global__ __launch_bounds__(256) void finalize_kernel(const float* __restrict__ absP,
                                                       const float* __restrict__ sqP,
                                                       float* __restrict__ out) {
    const int n = threadIdx.x;
    float av[V_], sv[V_];
    #pragma unroll
    for (int v = 0; v < V_; ++v) { av[v] = 0.0f; sv[v] = 0.0f; }
    #pragma unroll
    for (int c = 0; c < C_; ++c) {
        const int base = (n * C_ + c) * V_;
        #pragma unroll
        for (int v = 0; v < V_; ++v) {
            av[v] += absP[base + v];
            sv[v] += sqP[base + v];
        }
    }
    float sumAbs = 0.0f, sumW = 0.0f;
    #pragma unroll
    for (int v = 0; v < V_; ++v) { sumAbs += av[v]; sumW += av[v] * sv[v]; }
    float partial = (float)V_ * sumW / sumAbs;

    __shared__ float red[256];
    red[n] = partial;
    __syncthreads();
    for (int s = 128; s > 0; s >>= 1) {
        if (n < s) red[n] += red[n + s];
        __syncthreads();
    }
    if (n == 0) out[0] = red[0] / (float)((size_t)N_ * C_ * T_ * V_ * M_);
}

extern "C" void kernel_launch(void* const* d_in, const int* in_sizes, int n_in,
                              void* d_out, int out_size, void* d_ws, size_t ws_size,
                              hipStream_t stream) {
    const float* x = (const float*)d_in[0];
    const float* y = (const float*)d_in[1];
    float* out  = (float*)d_out;
    float* absP = (float*)d_ws;                 // NSLAB*V floats (disjoint partials)
    float* sqP  = absP + NSLAB * V_;            // NSLAB*V floats

    dim3 blk(V_, TY);                           // (25,20) = 500 threads
    slab_kernel<<<NSLAB, blk, 0, stream>>>(x, y, absP, sqP);

    finalize_kernel<<<1, 256, 0, stream>>>(absP, sqP, out);
}